// Round 3
// baseline (328.309 us; speedup 1.0000x reference)
//
#include <hip/hip_runtime.h>
#include <hip/hip_bf16.h>
#include <stdint.h>

// ---------- helpers ----------
typedef __attribute__((ext_vector_type(8))) short bf16x8;
typedef __attribute__((ext_vector_type(4))) float f32x4;

typedef __attribute__((address_space(3))) char      lds_char;
typedef __attribute__((address_space(3))) unsigned  lds_uint;
typedef __attribute__((address_space(1))) const unsigned g_uint;

__device__ __forceinline__ unsigned short f2bf(float f) {
    unsigned u = __float_as_uint(f);
    unsigned r = (u + 0x7fffu + ((u >> 16) & 1u)) >> 16;
    return (unsigned short)r;
}

__device__ __forceinline__ void async_copy16(const void* g, lds_char* l) {
    __builtin_amdgcn_global_load_lds((g_uint*)g, (lds_uint*)l, 16, 0, 0);
}

__device__ __forceinline__ float wsum(float v) {
#pragma unroll
    for (int d = 32; d > 0; d >>= 1) v += __shfl_xor(v, d, 64);
    return v;
}
__device__ __forceinline__ float wmax(float v) {
#pragma unroll
    for (int d = 32; d > 0; d >>= 1) v = fmaxf(v, __shfl_xor(v, d, 64));
    return v;
}

// ---------- problem constants ----------
#define BT_ROWS 32768   // B*T = 16*2048
#define FDIM    512     // F = K of gemm
#define NDIM    512     // N classes
#define KSEQ    8.0f

// ---------- kernel 1: cast f32 -> bf16 (x, w_both, w_values) ----------
__global__ __launch_bounds__(256) void cast_kernel(
    const float* __restrict__ x, const float* __restrict__ wb, const float* __restrict__ wv,
    unsigned short* __restrict__ xb, unsigned short* __restrict__ wbb, unsigned short* __restrict__ wvb)
{
    const int nx4 = (BT_ROWS * FDIM) >> 2;       // 4194304
    const int nw4 = (NDIM * FDIM) >> 2;          // 65536
    int i = blockIdx.x * 256 + threadIdx.x;
    const float4* src; unsigned short* dst; int j;
    if (i < nx4)            { src = (const float4*)x;  dst = xb;  j = i; }
    else if (i < nx4 + nw4) { src = (const float4*)wb; dst = wbb; j = i - nx4; }
    else if (i < nx4+2*nw4) { src = (const float4*)wv; dst = wvb; j = i - nx4 - nw4; }
    else return;
    float4 v = src[j];
    ushort4 o;
    o.x = f2bf(v.x); o.y = f2bf(v.y); o.z = f2bf(v.z); o.w = f2bf(v.w);
    *(ushort4*)(dst + 4*(size_t)j) = o;
}

// ---------- kernel 2: dual GEMM  C[m,n] = sum_k A[m,k]*W[n,k]  (bf16 in) ----------
// 128x128 tile, BK=32, 256 threads = 4 waves (2x2), each wave 64x64 via 4x4 frags of 16x16x32.
// BF16OUT=1: store bf16 to ushort C; BF16OUT=0: store f32 to float C.
template<int BF16OUT>
__global__ __launch_bounds__(256) void gemm_kernel(
    const unsigned short* __restrict__ A,
    const unsigned short* __restrict__ W0,
    const unsigned short* __restrict__ W1,
    void* C0v, void* C1v)
{
    __shared__ unsigned short lds[8192];   // A tile [128][32] then B tile [128][32], 16 KB
    const int Kd = FDIM;
    const int t = threadIdx.x, w = t >> 6, l = t & 63;
    const int bn = blockIdx.x, bm = blockIdx.y, mat = blockIdx.z;
    const unsigned short* Wm = mat ? W1 : W0;
    void* Cv = mat ? C1v : C0v;

    // staging addresses (per-lane global, wave-uniform LDS base)
    const int srow  = (w << 4) + (l >> 2);   // 0..63
    const int skoff = (l & 3) << 3;          // k elem offset 0/8/16/24
    const unsigned short* gA0 = A  + (size_t)(bm * 128 + srow) * Kd + skoff;
    const unsigned short* gA1 = gA0 + (size_t)64 * Kd;
    const unsigned short* gB0 = Wm + (size_t)(bn * 128 + srow) * Kd + skoff;
    const unsigned short* gB1 = gB0 + (size_t)64 * Kd;

    lds_char* lb = (lds_char*)lds;
    const unsigned offA0 = w * 1024;          // rows w*16.. , 64 B/row
    const unsigned offA1 = 4096 + w * 1024;
    const unsigned offB0 = 8192 + w * 1024;
    const unsigned offB1 = 12288 + w * 1024;

    const int wm = w >> 1, wn = w & 1;
    const int lr = l & 15, lk = (l >> 4) * 8;
    const unsigned short* lA = lds;
    const unsigned short* lB = lds + 4096;

    f32x4 acc[4][4] = {};

    const int ksteps = Kd / 32;   // 16
    for (int kk = 0; kk < ksteps; ++kk) {
        async_copy16(gA0, lb + offA0);
        async_copy16(gA1, lb + offA1);
        async_copy16(gB0, lb + offB0);
        async_copy16(gB1, lb + offB1);
        gA0 += 32; gA1 += 32; gB0 += 32; gB1 += 32;
        __syncthreads();   // drains vmcnt -> tiles ready

        bf16x8 ar[4], br[4];
#pragma unroll
        for (int r = 0; r < 4; ++r)
            ar[r] = *(const bf16x8*)&lA[(wm * 64 + r * 16 + lr) * 32 + lk];
#pragma unroll
        for (int c = 0; c < 4; ++c)
            br[c] = *(const bf16x8*)&lB[(wn * 64 + c * 16 + lr) * 32 + lk];
#pragma unroll
        for (int r = 0; r < 4; ++r)
#pragma unroll
            for (int c = 0; c < 4; ++c)
                acc[r][c] = __builtin_amdgcn_mfma_f32_16x16x32_bf16(ar[r], br[c], acc[r][c], 0, 0, 0);
        __syncthreads();   // protect LDS before next stage
    }

    // epilogue: C/D layout col = lane&15, row = (lane>>4)*4 + j  [m89]
    const int lg4 = (l >> 4) * 4;
#pragma unroll
    for (int r = 0; r < 4; ++r) {
        int row0 = bm * 128 + wm * 64 + r * 16 + lg4;
#pragma unroll
        for (int c = 0; c < 4; ++c) {
            int col = bn * 128 + wn * 64 + c * 16 + lr;
#pragma unroll
            for (int j = 0; j < 4; ++j) {
                if (BF16OUT) {
                    ((unsigned short*)Cv)[(size_t)(row0 + j) * NDIM + col] = f2bf(acc[r][c][j]);
                } else {
                    ((float*)Cv)[(size_t)(row0 + j) * NDIM + col] = acc[r][c][j];
                }
            }
        }
    }
}

// ---------- kernel 3: row-wise fused softmax / softmax / Newton / marginals / cumsum ----------
// one wave per row, 8 elems per lane; shuffle-only reductions and scan.
// BF16IN=1: logits are bf16 (ws). BF16IN=0: logits are f32 living in out sections 0/1
// (each wave reads only the rows it later overwrites -> race-free).
template<int BF16IN>
__global__ __launch_bounds__(256) void rowwise_kernel(
    const void* Lbv, const void* Lvv, float* out)
{
    const size_t S = (size_t)BT_ROWS * NDIM;   // per-output stride
    const int row = blockIdx.x * 4 + (threadIdx.x >> 6);
    const int l = threadIdx.x & 63;
    const size_t base = (size_t)row * NDIM + l * 8;

    float xb[8], xv[8];
    if (BF16IN) {
        uint4 ub = *(const uint4*)((const unsigned short*)Lbv + base);
        uint4 uv = *(const uint4*)((const unsigned short*)Lvv + base);
        unsigned b[4] = {ub.x, ub.y, ub.z, ub.w};
        unsigned v[4] = {uv.x, uv.y, uv.z, uv.w};
#pragma unroll
        for (int i = 0; i < 4; ++i) {
            xb[2*i]   = __uint_as_float(b[i] << 16);
            xb[2*i+1] = __uint_as_float(b[i] & 0xffff0000u);
            xv[2*i]   = __uint_as_float(v[i] << 16);
            xv[2*i+1] = __uint_as_float(v[i] & 0xffff0000u);
        }
    } else {
        const float4* fb = (const float4*)((const float*)Lbv + base);
        const float4* fv = (const float4*)((const float*)Lvv + base);
        float4 b0 = fb[0], b1 = fb[1], v0 = fv[0], v1 = fv[1];
        xb[0]=b0.x; xb[1]=b0.y; xb[2]=b0.z; xb[3]=b0.w;
        xb[4]=b1.x; xb[5]=b1.y; xb[6]=b1.z; xb[7]=b1.w;
        xv[0]=v0.x; xv[1]=v0.y; xv[2]=v0.z; xv[3]=v0.w;
        xv[4]=v1.x; xv[5]=v1.y; xv[6]=v1.z; xv[7]=v1.w;
    }

    // softmax 1 -> probs
    float m1 = xb[0];
#pragma unroll
    for (int i = 1; i < 8; ++i) m1 = fmaxf(m1, xb[i]);
    m1 = wmax(m1);
    float p[8]; float s1 = 0.f;
#pragma unroll
    for (int i = 0; i < 8; ++i) { p[i] = __expf(xb[i] - m1); s1 += p[i]; }
    s1 = wsum(s1);
    float inv1 = 1.f / s1;
#pragma unroll
    for (int i = 0; i < 8; ++i) p[i] *= inv1;

    // softmax 2 -> values = softmax(probs + logits_values)
    float tv[8];
    float m2 = -1e30f;
#pragma unroll
    for (int i = 0; i < 8; ++i) { tv[i] = p[i] + xv[i]; m2 = fmaxf(m2, tv[i]); }
    m2 = wmax(m2);
    float s2 = 0.f;
#pragma unroll
    for (int i = 0; i < 8; ++i) { tv[i] = __expf(tv[i] - m2); s2 += tv[i]; }
    s2 = wsum(s2);
    float inv2 = 1.f / s2;

    // Newton: alpha s.t. sum((1-p)^alpha) + K - N = 0
    float y[8];
#pragma unroll
    for (int i = 0; i < 8; ++i) y[i] = __logf(1.0f - p[i]);
    float alpha = KSEQ;
#pragma unroll
    for (int it = 0; it < 3; ++it) {
        float se = 0.f, sd = 0.f;
#pragma unroll
        for (int i = 0; i < 8; ++i) {
            float e = __expf(alpha * y[i]);
            se += e; sd += e * y[i];
        }
        se = wsum(se); sd = wsum(sd);
        float err = se + (KSEQ - (float)NDIM);
        alpha = alpha - err / sd;
    }

    // marginals = 1 - exp(alpha * y)
    float mg[8];
#pragma unroll
    for (int i = 0; i < 8; ++i) mg[i] = 1.0f - __expf(alpha * y[i]);

    // exclusive cumsum of p
    float loc = 0.f;
#pragma unroll
    for (int i = 0; i < 8; ++i) loc += p[i];
    float sc = loc;
#pragma unroll
    for (int d = 1; d < 64; d <<= 1) {
        float n = __shfl_up(sc, d, 64);
        if (l >= d) sc += n;
    }
    float run = sc - loc;   // exclusive lane prefix
    float cum[8];
#pragma unroll
    for (int i = 0; i < 8; ++i) { cum[i] = run; run += p[i]; }

    // stores: marginals, values, cumsum (two float4 each)
    float vals[8];
#pragma unroll
    for (int i = 0; i < 8; ++i) vals[i] = tv[i] * inv2;

    float4* omg = (float4*)(out + base);
    float4* ovl = (float4*)(out + S + base);
    float4* ocs = (float4*)(out + 2 * S + base);
    omg[0] = make_float4(mg[0], mg[1], mg[2], mg[3]);
    omg[1] = make_float4(mg[4], mg[5], mg[6], mg[7]);
    ovl[0] = make_float4(vals[0], vals[1], vals[2], vals[3]);
    ovl[1] = make_float4(vals[4], vals[5], vals[6], vals[7]);
    ocs[0] = make_float4(cum[0], cum[1], cum[2], cum[3]);
    ocs[1] = make_float4(cum[4], cum[5], cum[6], cum[7]);
}

// ---------- launch ----------
extern "C" void kernel_launch(void* const* d_in, const int* in_sizes, int n_in,
                              void* d_out, int out_size, void* d_ws, size_t ws_size,
                              hipStream_t stream) {
    const float* x  = (const float*)d_in[0];
    const float* wb = (const float*)d_in[1];
    const float* wv = (const float*)d_in[2];
    float* out = (float*)d_out;
    char* ws = (char*)d_ws;
    const size_t S = (size_t)BT_ROWS * NDIM;

    // workspace layout (bytes)
    unsigned short* xb  = (unsigned short*)(ws);                 // 32 MB
    unsigned short* wbb = (unsigned short*)(ws + 33554432);      // 512 KB
    unsigned short* wvb = (unsigned short*)(ws + 34078720);      // 512 KB
    unsigned short* lgb = (unsigned short*)(ws + 34603008);      // 32 MB (plan A)
    unsigned short* lgv = (unsigned short*)(ws + 68157440);      // 32 MB (plan A)
    const bool planA = ws_size >= (size_t)101711872;

    // 1) cast all inputs to bf16
    {
        int total4 = (BT_ROWS * FDIM + 2 * NDIM * FDIM) / 4;
        int blocks = (total4 + 255) / 256;
        cast_kernel<<<blocks, 256, 0, stream>>>(x, wb, wv, xb, wbb, wvb);
    }
    // 2) dual GEMM -> logits
    dim3 grid(NDIM / 128, BT_ROWS / 128, 2);
    if (planA) {
        gemm_kernel<1><<<grid, 256, 0, stream>>>(xb, wbb, wvb, (void*)lgb, (void*)lgv);
        rowwise_kernel<1><<<BT_ROWS / 4, 256, 0, stream>>>(lgb, lgv, out);
    } else {
        // plan B: f32 logits staged in out sections 0/1, overwritten row-by-row
        gemm_kernel<0><<<grid, 256, 0, stream>>>(xb, wbb, wvb, (void*)out, (void*)(out + S));
        rowwise_kernel<0><<<BT_ROWS / 4, 256, 0, stream>>>(out, out + S, out);
    }
}